// Round 1
// 326.516 us; speedup vs baseline: 1.0384x; 1.0384x over previous
//
#include <hip/hip_runtime.h>

#define NN 2048   // atoms
#define CA 128    // c_atom
#define CR 389    // c_ref feature dim
#define CP 16     // c_atom_pair

typedef float nfloat4 __attribute__((ext_vector_type(4)));  // clang-native: ok for nontemporal builtins

// ---------------- cl = concat(feats) @ W_feats + b_feats ----------------
// 256 blocks x 256 threads (1 block/CU). Thread = (atom a = tid>>5 of 8,
// channel quad q = tid&31). Each thread computes 4 channels so Wf is read
// as dwordx4 (lanes 0-31 cover 512 B contiguous; lanes 32-63 broadcast the
// same row for the second atom). 4x fewer load instructions per output
// than the scalar-per-channel mapping; unroll 16 keeps 16 loads in flight
// to hide L2 latency at low occupancy.
__global__ __launch_bounds__(256) void cl_kernel(
    const float* __restrict__ pos, const float* __restrict__ charge,
    const float* __restrict__ mask, const float* __restrict__ elem,
    const float* __restrict__ names, const float* __restrict__ Wf,
    const float* __restrict__ bfeats, float* __restrict__ cl)
{
    __shared__ float ft[8][CR];
    const int tid = threadIdx.x;
    const int n0 = blockIdx.x * 8;

    // Gather concatenated features: [pos(3),charge(1),mask(1),elem(128),names(256)]
    for (int idx = tid; idx < 8 * CR; idx += 256) {
        int a = idx / CR;
        int k = idx - a * CR;          // consecutive k -> coalesced elem/names
        int n = n0 + a;
        float v;
        if (k < 3)         v = pos[n * 3 + k];
        else if (k == 3)   v = charge[n];
        else if (k == 4)   v = mask[n];
        else if (k < 133)  v = elem[n * 128 + (k - 5)];
        else               v = names[n * 256 + (k - 133)];
        ft[a][k] = v;
    }
    __syncthreads();

    const int q = tid & 31;            // channel quad: channels 4q..4q+3
    const int a = tid >> 5;            // atom within block
    const float* fa = ft[a];
    const float* wp = Wf + q * 4;

    nfloat4 acc = {0.f, 0.f, 0.f, 0.f};
    #pragma unroll 16                  // 16 independent dwordx4 Wf loads in flight
    for (int k = 0; k < CR; ++k) {
        const float f = fa[k];         // LDS broadcast (uniform per half-wave)
        const nfloat4 w = *(const nfloat4*)(wp + (size_t)k * CA);  // 16B aligned
        acc[0] = fmaf(f, w[0], acc[0]);
        acc[1] = fmaf(f, w[1], acc[1]);
        acc[2] = fmaf(f, w[2], acc[2]);
        acc[3] = fmaf(f, w[3], acc[3]);
    }
    acc += *(const nfloat4*)(bfeats + q * 4);
    __builtin_nontemporal_store(acc, (nfloat4*)(cl + (size_t)(n0 + a) * CA + q * 4));
}

// ------- plm[l][m][c] = v * (dlm . Woff[:,c] + inv_sq*Winv[c] + K[c]) -------
// K[c] = Wvm[c] + boff[c] + binv[c] + bvm[c]   (v in {0,1}, v^2 = v)
// One block per l. Thread t = (pair slot p = t>>2, channel quad q = t&3):
// each wave's single float4 store covers 64 lanes x 16 B = 1 KB CONTIGUOUS
// (full cache lines -> no read-for-ownership), nontemporal (bypass L2).
// 1/(1+d^2) via v_rcp_f32 (1-ulp; tolerance budget is 2e-3) instead of the
// ~10-instr IEEE div sequence, which was computed redundantly in all 4
// channel-quad lanes.
__global__ __launch_bounds__(256) void plm_kernel(
    const float* __restrict__ pos, const int* __restrict__ uid,
    const float* __restrict__ Woff, const float* __restrict__ boff,
    const float* __restrict__ Winv, const float* __restrict__ binv,
    const float* __restrict__ Wvm, const float* __restrict__ bvm,
    float* __restrict__ out)
{
    const int tid = threadIdx.x;
    const int q = tid & 3;              // channel quad: channels 4q..4q+3
    const int p = tid >> 2;             // pair slot 0..63

    float w0[4], w1[4], w2[4], wi[4], kk[4];
    #pragma unroll
    for (int i = 0; i < 4; ++i) {
        int c = q * 4 + i;
        w0[i] = Woff[c];
        w1[i] = Woff[CP + c];
        w2[i] = Woff[2 * CP + c];
        wi[i] = Winv[c];
        kk[i] = Wvm[c] + boff[c] + binv[c] + bvm[c];
    }

    const int l = blockIdx.x;
    const float plx = pos[l * 3 + 0];
    const float ply = pos[l * 3 + 1];
    const float plz = pos[l * 3 + 2];
    const int ul = uid[l];
    nfloat4* __restrict__ dst = (nfloat4*)(out + (size_t)l * NN * CP);

    #pragma unroll 4
    for (int j = 0; j < NN / 64; ++j) {   // 32 iterations, 64 pairs each
        const int m = j * 64 + p;
        const float dx = plx - pos[m * 3 + 0];
        const float dy = ply - pos[m * 3 + 1];
        const float dz = plz - pos[m * 3 + 2];
        const float inv = __builtin_amdgcn_rcpf(1.0f + dx * dx + dy * dy + dz * dz);
        const unsigned sel = (uid[m] == ul) ? 0xFFFFFFFFu : 0u;

        float rx = fmaf(dx, w0[0], fmaf(dy, w1[0], fmaf(dz, w2[0], fmaf(inv, wi[0], kk[0]))));
        float ry = fmaf(dx, w0[1], fmaf(dy, w1[1], fmaf(dz, w2[1], fmaf(inv, wi[1], kk[1]))));
        float rz = fmaf(dx, w0[2], fmaf(dy, w1[2], fmaf(dz, w2[2], fmaf(inv, wi[2], kk[2]))));
        float rw = fmaf(dx, w0[3], fmaf(dy, w1[3], fmaf(dz, w2[3], fmaf(inv, wi[3], kk[3]))));

        // v==0 -> exact +0.0f via bitwise AND (branchless, every element written)
        unsigned ux = __float_as_uint(rx) & sel;
        unsigned uy = __float_as_uint(ry) & sel;
        unsigned uz = __float_as_uint(rz) & sel;
        unsigned uw = __float_as_uint(rw) & sel;

        nfloat4 r;
        r.x = __uint_as_float(ux);
        r.y = __uint_as_float(uy);
        r.z = __uint_as_float(uz);
        r.w = __uint_as_float(uw);

        __builtin_nontemporal_store(r, dst + j * 256 + tid);  // 1 KB contiguous/wave
    }
}

extern "C" void kernel_launch(void* const* d_in, const int* in_sizes, int n_in,
                              void* d_out, int out_size, void* d_ws, size_t ws_size,
                              hipStream_t stream)
{
    const float* pos    = (const float*)d_in[0];
    const float* charge = (const float*)d_in[1];
    const float* mask   = (const float*)d_in[2];
    const float* elem   = (const float*)d_in[3];
    const float* names  = (const float*)d_in[4];
    const int*   uid    = (const int*)  d_in[5];
    const float* Wf     = (const float*)d_in[6];
    const float* bfeats = (const float*)d_in[7];
    const float* Woff   = (const float*)d_in[8];
    const float* boff   = (const float*)d_in[9];
    const float* Winv   = (const float*)d_in[10];
    const float* binv   = (const float*)d_in[11];
    const float* Wvm    = (const float*)d_in[12];
    const float* bvm    = (const float*)d_in[13];

    float* cl  = (float*)d_out;
    float* plm = (float*)d_out + (size_t)NN * CA;

    cl_kernel<<<NN / 8, 256, 0, stream>>>(pos, charge, mask, elem, names, Wf, bfeats, cl);
    plm_kernel<<<NN, 256, 0, stream>>>(pos, uid, Woff, boff, Winv, binv, Wvm, bvm, plm);
}